// Round 11
// baseline (12831.070 us; speedup 1.0000x reference)
//
#include <hip/hip_runtime.h>
#include <math.h>

#define N_PTS 32768
#define M_SEL 8192
#define K_NBR 64
#define F_IN  64
#define H_MID 128
#define C_OUT 128
#define NCELL 2048      // 16 x 16 x 8 grid, owner-swizzled cell index
#define CAP   192       // per-centroid candidate cap
#define NWF   8         // waves in fps block (one owner per wave)
#define NTF   (NWF * 64)

// ---------- helpers ----------

__device__ __forceinline__ int iclamp(int v, int hi) {
    return v < 0 ? 0 : (v > hi ? hi : v);
}

// owner-swizzled cell id: low bit of (ix,iy,iz) -> owner wave (8 waves),
// so any 3x3x3 spatial neighborhood spreads across all 8 waves.
__device__ __forceinline__ int cell_idx(int ix, int iy, int iz) {
    int w    = (ix & 1) | ((iy & 1) << 1) | ((iz & 1) << 2);
    int rest = ((iz >> 1) * 8 + (iy >> 1)) * 8 + (ix >> 1);      // [0,256)
    return (w << 8) | rest;
}

__device__ __forceinline__ int cell_of(float px, float py, float pz) {
    int ix = iclamp((int)(px * 16.0f), 15);
    int iy = iclamp((int)(py * 16.0f), 15);
    int iz = iclamp((int)(pz * 8.0f), 7);
    return cell_idx(ix, iy, iz);
}

// Bit-exact replica of numpy: ((dx*dx + dy*dy) + dz*dz), rn, no fma.
__device__ __forceinline__ float d2_exact(float ax, float ay, float az,
                                          float bx, float by, float bz) {
#pragma clang fp contract(off)
    float dx = ax - bx, dy = ay - by, dz = az - bz;
    return (dx * dx + dy * dy) + dz * dz;
}

__device__ __forceinline__ unsigned long long umax64(unsigned long long a,
                                                     unsigned long long b) {
    return a > b ? a : b;
}

// pack: [63:32] mind_bits, [29:15] orig^0x7FFF, [14:0] slot.
// Lex order = (mind, -orig); slot never decides (orig unique).
__device__ __forceinline__ unsigned long long make_pk(float nv, unsigned int o,
                                                      unsigned int slot) {
    return ((unsigned long long)__float_as_uint(nv) << 32)
         | ((unsigned long long)((o ^ 0x7FFFu) & 0x7FFFu) << 15)
         | (unsigned long long)slot;
}

// ---------- binning ----------

__global__ void bin_count_kernel(const float* __restrict__ pos, int* __restrict__ cnt) {
    int i = blockIdx.x * blockDim.x + threadIdx.x;
    if (i < N_PTS) {
        atomicAdd(&cnt[cell_of(pos[3*i], pos[3*i+1], pos[3*i+2])], 1);
    }
}

// inclusive Hillis-Steele over 2048 with 1024 threads (2 elements each)
__global__ void scan_kernel(const int* __restrict__ cnt, int* __restrict__ start,
                            int* __restrict__ fill) {
    __shared__ int s[NCELL];
    int t = threadIdx.x;
    int v0 = cnt[t], v1 = cnt[t + 1024];
    s[t] = v0; s[t + 1024] = v1;
    __syncthreads();
    for (int off = 1; off < NCELL; off <<= 1) {
        int a0 = (t >= off) ? s[t - off] : 0;
        int i1 = t + 1024;
        int a1 = (i1 >= off) ? s[i1 - off] : 0;
        __syncthreads();
        s[t] += a0; s[i1] += a1;
        __syncthreads();
    }
    start[t] = s[t] - v0;                fill[t] = s[t] - v0;
    start[t + 1024] = s[t + 1024] - v1;  fill[t + 1024] = s[t + 1024] - v1;
    if (t == 1023) start[NCELL] = s[NCELL - 1];
}

// pq[slot] = (x, y, z, orig_index_as_float_bits)
__global__ void scatter_kernel(const float* __restrict__ pos, int* __restrict__ fill,
                               float4* __restrict__ pq) {
    int i = blockIdx.x * blockDim.x + threadIdx.x;
    if (i < N_PTS) {
        float px = pos[3*i], py = pos[3*i+1], pz = pos[3*i+2];
        int c = cell_of(px, py, pz);
        int slot = atomicAdd(&fill[c], 1);
        pq[slot] = make_float4(px, py, pz, __int_as_float(i));
    }
}

// ---------- FPS ----------
// 512 threads = 8 waves (2/SIMD); wave w OWNS cells [256w,256w+256) and their
// points (wave-private s_mind / s_sub / s_wlist => DS in-order, no barrier
// around them). ONE __syncthreads per iteration (publish wave-bests).
// B: 16-lane groups, cells processed PAIR-wise with all loads issued before
// dependent compute (single round-trip). Per-cell max via one ds_max_u64.

__global__ __launch_bounds__(NTF) void fps_kernel(
        const float4* __restrict__ pq, const int* __restrict__ cstart,
        const float* __restrict__ pos, int* __restrict__ sel) {
    __shared__ float s_mind[N_PTS];                    // 128 KB (owner-private)
    __shared__ unsigned long long s_sub[NCELL];        // 16 KB (owner-private)
    __shared__ unsigned long long s_redw[NWF][8];      // 512 B (owner-private)
    __shared__ __align__(16) unsigned long long s_gb[2][NWF];  // cross-wave, dbuf
    __shared__ unsigned int s_wlist[NWF][256];         // 8 KB  (owner-private)

    const int tid  = threadIdx.x;
    const int lane = tid & 63;
    const int wid  = tid >> 6;
    const int g    = lane >> 4;     // 16-lane group 0..3
    const int gl   = lane & 15;
    const unsigned long long lmask_lt = (1ULL << lane) - 1ULL;

    for (int i = tid; i < N_PTS; i += NTF) s_mind[i] = INFINITY;
    if (tid == 0) sel[0] = 0;

    // own-cell descriptors & geometry (4 cells per lane)
    float lox[4], loy[4], loz[4];
    unsigned int ent[4];
    unsigned long long vb[4];       // per-cell best, persistent in registers
    bool fmask[4];
    #pragma unroll
    for (int k = 0; k < 4; ++k) {
        const int rest = lane + (k << 6);               // [0,256)
        const int c = (wid << 8) | rest;
        const int ix = ((rest & 7) << 1)        | (wid & 1);
        const int iy = (((rest >> 3) & 7) << 1) | ((wid >> 1) & 1);
        const int iz = ((rest >> 6) << 1)       | ((wid >> 2) & 1);
        lox[k] = (float)ix * 0.0625f;
        loy[k] = (float)iy * 0.0625f;
        loz[k] = (float)iz * 0.125f;
        const int cs = cstart[c], ce = cstart[c + 1];
        int len = ce - cs; if (len > 511) len = 511;   // statistically impossible
        ent[k] = (unsigned)cs | ((unsigned)len << 15) | ((unsigned)rest << 24);
        // +inf sentinel => every nonempty cell flagged on iteration 1
        vb[k] = (ce > cs) ? ((0x7F800000ULL << 32) | 0x3FFFFFFFULL) : 0ULL;
    }

    int nfw = 0;
    float px = pos[0], py = pos[1], pz = pos[2];

    auto flag_assign = [&]() {
        unsigned int cnt = 0;
        #pragma unroll
        for (int k = 0; k < 4; ++k) {
            const float cm = __uint_as_float((unsigned)(vb[k] >> 32));
            float dx = fmaxf(fmaxf(lox[k] - px, px - (lox[k] + 0.0625f)), 0.0f);
            float dy = fmaxf(fmaxf(loy[k] - py, py - (loy[k] + 0.0625f)), 0.0f);
            float dz = fmaxf(fmaxf(loz[k] - pz, pz - (loz[k] + 0.125f)), 0.0f);
            float lb2 = dx * dx + dy * dy + dz * dz;
            bool fl = (lb2 * 0.999f < cm);             // conservative skip bound
            fmask[k] = fl;
            unsigned long long b = __ballot(fl);
            unsigned rank = cnt + (unsigned)__popcll(b & lmask_lt);
            if (fl) s_wlist[wid][rank] = ent[k];
            cnt += (unsigned)__popcll(b);
        }
        nfw = (int)cnt;
    };
    flag_assign();
    __syncthreads();     // covers s_mind init (striped across waves)

    for (int m = 1; m < M_SEL; ++m) {
        // ---- B: own flagged cells, PAIR-wise per 16-lane group; all loads
        //      for both cells issued before any dependent compute ----
        if (lane < 8) s_redw[wid][lane] = 0ULL;
        for (int i = g; i < nfw; i += 8) {
            const unsigned e1 = s_wlist[wid][i];
            const int iP = i + 4;
            const bool have2 = (iP < nfw);
            const unsigned e2 = have2 ? s_wlist[wid][iP] : 0u;

            const int cs1 = (int)(e1 & 0x7FFFu);
            const int ce1 = cs1 + (int)((e1 >> 15) & 0x1FFu);
            const int c1  = (wid << 8) | (int)(e1 >> 24);
            const int cs2 = (int)(e2 & 0x7FFFu);
            const int ce2 = have2 ? cs2 + (int)((e2 >> 15) & 0x1FFu) : 0;
            const int c2  = (wid << 8) | (int)(e2 >> 24);

            if (gl == 0) {
                s_sub[c1] = 0ULL;                      // in-order before atomics
                if (have2) s_sub[c2] = 0ULL;
            }

            const int j1a = cs1 + gl, j1b = j1a + 16;
            const int j2a = cs2 + gl, j2b = j2a + 16;
            const bool h1a = j1a < ce1, h1b = j1b < ce1;
            const bool h2a = j2a < ce2, h2b = j2b < ce2;

            float4 q1a, q1b, q2a, q2b;
            float md1a = 0.0f, md1b = 0.0f, md2a = 0.0f, md2b = 0.0f;
            if (h1a) { q1a = pq[j1a]; md1a = s_mind[j1a]; }
            if (h1b) { q1b = pq[j1b]; md1b = s_mind[j1b]; }
            if (h2a) { q2a = pq[j2a]; md2a = s_mind[j2a]; }
            if (h2b) { q2b = pq[j2b]; md2b = s_mind[j2b]; }

            if (h1a) {
                const float d2 = d2_exact(q1a.x, q1a.y, q1a.z, px, py, pz);
                const float nv = d2 < md1a ? d2 : md1a;
                s_mind[j1a] = nv;
                atomicMax(&s_sub[c1],
                          make_pk(nv, (unsigned)__float_as_int(q1a.w), (unsigned)j1a));
            }
            if (h1b) {
                const float d2 = d2_exact(q1b.x, q1b.y, q1b.z, px, py, pz);
                const float nv = d2 < md1b ? d2 : md1b;
                s_mind[j1b] = nv;
                atomicMax(&s_sub[c1],
                          make_pk(nv, (unsigned)__float_as_int(q1b.w), (unsigned)j1b));
            }
            if (h2a) {
                const float d2 = d2_exact(q2a.x, q2a.y, q2a.z, px, py, pz);
                const float nv = d2 < md2a ? d2 : md2a;
                s_mind[j2a] = nv;
                atomicMax(&s_sub[c2],
                          make_pk(nv, (unsigned)__float_as_int(q2a.w), (unsigned)j2a));
            }
            if (h2b) {
                const float d2 = d2_exact(q2b.x, q2b.y, q2b.z, px, py, pz);
                const float nv = d2 < md2b ? d2 : md2b;
                s_mind[j2b] = nv;
                atomicMax(&s_sub[c2],
                          make_pk(nv, (unsigned)__float_as_int(q2b.w), (unsigned)j2b));
            }
            // rare tails: cells with more than 32 points
            for (int j = cs1 + gl + 32; j < ce1; j += 16) {
                const float4 q = pq[j];
                const float d2 = d2_exact(q.x, q.y, q.z, px, py, pz);
                const float old = s_mind[j];
                const float nv = d2 < old ? d2 : old;
                s_mind[j] = nv;
                atomicMax(&s_sub[c1],
                          make_pk(nv, (unsigned)__float_as_int(q.w), (unsigned)j));
            }
            if (have2) {
                for (int j = cs2 + gl + 32; j < ce2; j += 16) {
                    const float4 q = pq[j];
                    const float d2 = d2_exact(q.x, q.y, q.z, px, py, pz);
                    const float old = s_mind[j];
                    const float nv = d2 < old ? d2 : old;
                    s_mind[j] = nv;
                    atomicMax(&s_sub[c2],
                              make_pk(nv, (unsigned)__float_as_int(q.w), (unsigned)j));
                }
            }
        }

        // ---- D: consolidate own flagged cells, own-wave argmax (no barrier:
        //      all data owner-private, DS in-order per wave) ----
        #pragma unroll
        for (int k = 0; k < 4; ++k)
            if (fmask[k]) vb[k] = s_sub[(wid << 8) | (lane + (k << 6))];
        unsigned long long best = umax64(umax64(vb[0], vb[1]),
                                         umax64(vb[2], vb[3]));
        atomicMax(&s_redw[wid][lane & 7], best);
        #pragma unroll
        for (int i = 0; i < 8; ++i) best = umax64(best, s_redw[wid][i]);
        if (lane == 0) s_gb[m & 1][wid] = best;

        __syncthreads();     // the ONE barrier: publish wave-bests

        // ---- E: global argmax over 8 wave-bests (4 x b128 + max tree) ----
        const ulonglong2* gp = (const ulonglong2*)&s_gb[m & 1][0];
        const ulonglong2 g0 = gp[0], g1 = gp[1], g2 = gp[2], g3 = gp[3];
        unsigned long long gb = umax64(
            umax64(umax64(g0.x, g0.y), umax64(g1.x, g1.y)),
            umax64(umax64(g2.x, g2.y), umax64(g3.x, g3.y)));
        const unsigned orig = (~(unsigned)(gb >> 15)) & 0x7FFFu;
        const unsigned slot = (unsigned)gb & 0x7FFFu;
        if (tid == 0) sel[m] = (int)orig;
        const float4 qp = pq[slot];                    // L1/L2-hot broadcast
        px = qp.x; py = qp.y; pz = qp.z;

        // ---- F: own flags + own list for next iteration ----
        flag_assign();
    }
}

// ---------- ball query: up-to-64 nearest in-radius (one wave / centroid) ----------

__global__ __launch_bounds__(256) void ballq_kernel(
        const float* __restrict__ pos,
        const float4* __restrict__ pq,
        const int* __restrict__ cstart, const int* __restrict__ sel,
        int* __restrict__ nbr, int* __restrict__ ncnt) {
    __shared__ float s_d2[4][CAP];
    __shared__ int   s_o[4][CAP];
    __shared__ int   s_cnt[4];

    const int wid  = threadIdx.x >> 6;
    const int lane = threadIdx.x & 63;
    const int m = blockIdx.x * 4 + wid;

    if (lane == 0) s_cnt[wid] = 0;
    __syncthreads();

    int sidx = sel[m];
    float cx = pos[3*sidx], cy = pos[3*sidx+1], cz = pos[3*sidx+2];
    int ix = iclamp((int)(cx * 16.0f), 15);
    int iy = iclamp((int)(cy * 16.0f), 15);
    int iz = iclamp((int)(cz * 8.0f), 7);
    const float r2 = (float)(0.08 * 0.08);

    // cells reachable within r=0.08: +-2 in x,y (0.0625), +-1 in z (0.125)
    for (int dz = -1; dz <= 1; ++dz) {
        int z = iz + dz; if (z < 0 || z > 7) continue;
        for (int dy = -2; dy <= 2; ++dy) {
            int y = iy + dy; if (y < 0 || y > 15) continue;
            for (int dx = -2; dx <= 2; ++dx) {
                int xx = ix + dx; if (xx < 0 || xx > 15) continue;
                int c = cell_idx(xx, y, z);
                int cs = cstart[c], ce = cstart[c + 1];
                for (int j = cs + lane; j < ce; j += 64) {
                    float4 q = pq[j];
                    float d2 = d2_exact(cx, cy, cz, q.x, q.y, q.z);
                    if (d2 <= r2) {
                        int slot = atomicAdd(&s_cnt[wid], 1);
                        if (slot < CAP) { s_d2[wid][slot] = d2; s_o[wid][slot] = __float_as_int(q.w); }
                    }
                }
            }
        }
    }
    __syncthreads();

    int cnt = s_cnt[wid];
    if (cnt > CAP) cnt = CAP;
    if (cnt <= K_NBR) {
        if (lane < cnt) nbr[m * K_NBR + lane] = s_o[wid][lane];
        if (lane == 0) ncnt[m] = cnt;
    } else {
        // exact (d2, orig-index) lexicographic rank -> keep 64 nearest (matches top_k)
        for (int i = lane; i < cnt; i += 64) {
            float d2 = s_d2[wid][i];
            int   o  = s_o[wid][i];
            int rank = 0;
            for (int j = 0; j < cnt; ++j) {
                float dj = s_d2[wid][j];
                int   oj = s_o[wid][j];
                rank += (dj < d2 || (dj == d2 && oj < o)) ? 1 : 0;
            }
            if (rank < K_NBR) nbr[m * K_NBR + rank] = o;
        }
        if (lane == 0) ncnt[m] = K_NBR;
    }
}

// ---------- PointConv MLP + masked max-pool (fp32, one block / centroid) ----------

__global__ __launch_bounds__(256) void mlp_kernel(
        const float* __restrict__ x, const float* __restrict__ pos,
        const float* __restrict__ W1, const float* __restrict__ b1,
        const float* __restrict__ W2, const float* __restrict__ b2,
        const int* __restrict__ sel, const int* __restrict__ nbr,
        const int* __restrict__ ncnt, float* __restrict__ out) {
    __shared__ __align__(16) float feat[64][68];   // 67 used + pad
    __shared__ __align__(16) float h[64][H_MID];
    __shared__ float part[2][H_MID];

    const int m = blockIdx.x;
    const int tid = threadIdx.x;
    const int cnt = ncnt[m];
    const int s = sel[m];
    float cx = pos[3*s], cy = pos[3*s+1], cz = pos[3*s+2];

    for (int i = tid; i < 64 * 68; i += 256) ((float*)feat)[i] = 0.0f;
    __syncthreads();

    for (int i = tid; i < cnt * F_IN; i += 256) {
        int k = i >> 6, f = i & 63;
        int j = nbr[m * K_NBR + k];
        feat[k][f] = x[(size_t)j * F_IN + f];
    }
    if (tid < 64 && tid < cnt) {
        int j = nbr[m * K_NBR + tid];
        feat[tid][64] = pos[3*j]     - cx;
        feat[tid][65] = pos[3*j + 1] - cy;
        feat[tid][66] = pos[3*j + 2] - cz;
    }
    __syncthreads();

    const int c = tid & 127;
    const int half = tid >> 7;

    for (int k = half; k < 64; k += 2) {
        float acc = b1[c];
        const float4* fr = (const float4*)&feat[k][0];
#pragma unroll
        for (int f4 = 0; f4 < 16; ++f4) {
            float4 fv = fr[f4];
            int fb = f4 * 4;
            acc = fmaf(fv.x, W1[(fb    ) * H_MID + c], acc);
            acc = fmaf(fv.y, W1[(fb + 1) * H_MID + c], acc);
            acc = fmaf(fv.z, W1[(fb + 2) * H_MID + c], acc);
            acc = fmaf(fv.w, W1[(fb + 3) * H_MID + c], acc);
        }
        acc = fmaf(feat[k][64], W1[64 * H_MID + c], acc);
        acc = fmaf(feat[k][65], W1[65 * H_MID + c], acc);
        acc = fmaf(feat[k][66], W1[66 * H_MID + c], acc);
        h[k][c] = fmaxf(acc, 0.0f);
    }
    __syncthreads();

    float best = -INFINITY;
    for (int k = half; k < cnt; k += 2) {
        float acc = 0.0f;
        const float4* hr = (const float4*)&h[k][0];
#pragma unroll
        for (int q = 0; q < 32; ++q) {
            float4 hv = hr[q];
            int hb = q * 4;
            acc = fmaf(hv.x, W2[(hb    ) * C_OUT + c], acc);
            acc = fmaf(hv.y, W2[(hb + 1) * C_OUT + c], acc);
            acc = fmaf(hv.z, W2[(hb + 2) * C_OUT + c], acc);
            acc = fmaf(hv.w, W2[(hb + 3) * C_OUT + c], acc);
        }
        best = fmaxf(best, acc);
    }
    part[half][c] = best;
    __syncthreads();
    if (tid < 128) {
        out[(size_t)m * C_OUT + tid] = fmaxf(part[0][tid], part[1][tid]) + b2[tid];
    }
}

// ---------- outputs 2 & 3 ----------

__global__ void tail_kernel(const float* __restrict__ pos, const int* __restrict__ sel,
                            float* __restrict__ out_selpos, float* __restrict__ out_batch) {
    int i = blockIdx.x * blockDim.x + threadIdx.x;
    if (i < M_SEL) {
        int s = sel[i];
        out_selpos[3*i]     = pos[3*s];
        out_selpos[3*i + 1] = pos[3*s + 1];
        out_selpos[3*i + 2] = pos[3*s + 2];
        out_batch[i] = 0.0f;
    }
}

// ---------- launch ----------

extern "C" void kernel_launch(void* const* d_in, const int* in_sizes, int n_in,
                              void* d_out, int out_size, void* d_ws, size_t ws_size,
                              hipStream_t stream) {
    const float* x   = (const float*)d_in[0];
    const float* pos = (const float*)d_in[1];
    // d_in[2] = batch (int64, all zeros) — unused
    const float* W1 = (const float*)d_in[3];
    const float* b1 = (const float*)d_in[4];
    const float* W2 = (const float*)d_in[5];
    const float* b2 = (const float*)d_in[6];

    float* out        = (float*)d_out;
    float* out_selpos = out + (size_t)M_SEL * C_OUT;
    float* out_batch  = out_selpos + (size_t)M_SEL * 3;

    char* ws = (char*)d_ws;
    size_t off = 0;
    auto alloc = [&](size_t bytes) -> void* {
        void* p = ws + off;
        off = (off + bytes + 255) & ~(size_t)255;
        return p;
    };
    int*    cnt    = (int*)alloc(NCELL * 4);
    int*    cstart = (int*)alloc((NCELL + 1) * 4);
    int*    cfill  = (int*)alloc(NCELL * 4);
    float4* pq     = (float4*)alloc((size_t)N_PTS * 16);
    int*    sel    = (int*)alloc(M_SEL * 4);
    int*    nbr    = (int*)alloc((size_t)M_SEL * K_NBR * 4);
    int*    ncnt   = (int*)alloc(M_SEL * 4);
    (void)ws_size; (void)in_sizes; (void)n_in; (void)out_size;

    (void)hipMemsetAsync(cnt, 0, NCELL * 4, stream);
    bin_count_kernel<<<N_PTS / 256, 256, 0, stream>>>(pos, cnt);
    scan_kernel<<<1, 1024, 0, stream>>>(cnt, cstart, cfill);
    scatter_kernel<<<N_PTS / 256, 256, 0, stream>>>(pos, cfill, pq);
    fps_kernel<<<1, NTF, 0, stream>>>(pq, cstart, pos, sel);
    ballq_kernel<<<M_SEL / 4, 256, 0, stream>>>(pos, pq, cstart, sel, nbr, ncnt);
    mlp_kernel<<<M_SEL, 256, 0, stream>>>(x, pos, W1, b1, W2, b2, sel, nbr, ncnt, out);
    tail_kernel<<<(M_SEL + 255) / 256, 256, 0, stream>>>(pos, sel, out_selpos, out_batch);
}

// Round 12
// 12751.653 us; speedup vs baseline: 1.0062x; 1.0062x over previous
//
#include <hip/hip_runtime.h>
#include <math.h>

#define N_PTS 32768
#define M_SEL 8192
#define K_NBR 64
#define F_IN  64
#define H_MID 128
#define C_OUT 128
#define NCELL 2048      // 16 x 16 x 8 grid, owner-swizzled cell index
#define CAP   192       // per-centroid candidate cap
#define NWF   8         // waves in fps block (one owner per wave)
#define NTF   (NWF * 64)

// ---------- helpers ----------

__device__ __forceinline__ int iclamp(int v, int hi) {
    return v < 0 ? 0 : (v > hi ? hi : v);
}

// owner-swizzled cell id: low bit of (ix,iy,iz) -> owner wave (8 waves),
// so any 3x3x3 spatial neighborhood spreads across all 8 waves.
__device__ __forceinline__ int cell_idx(int ix, int iy, int iz) {
    int w    = (ix & 1) | ((iy & 1) << 1) | ((iz & 1) << 2);
    int rest = ((iz >> 1) * 8 + (iy >> 1)) * 8 + (ix >> 1);      // [0,256)
    return (w << 8) | rest;
}

__device__ __forceinline__ int cell_of(float px, float py, float pz) {
    int ix = iclamp((int)(px * 16.0f), 15);
    int iy = iclamp((int)(py * 16.0f), 15);
    int iz = iclamp((int)(pz * 8.0f), 7);
    return cell_idx(ix, iy, iz);
}

// Bit-exact replica of numpy: ((dx*dx + dy*dy) + dz*dz), rn, no fma.
__device__ __forceinline__ float d2_exact(float ax, float ay, float az,
                                          float bx, float by, float bz) {
#pragma clang fp contract(off)
    float dx = ax - bx, dy = ay - by, dz = az - bz;
    return (dx * dx + dy * dy) + dz * dz;
}

__device__ __forceinline__ unsigned long long umax64(unsigned long long a,
                                                     unsigned long long b) {
    return a > b ? a : b;
}

// pack: [63:32] mind_bits, [29:15] orig^0x7FFF, [14:0] slot.
// Lex order = (mind, -orig); slot never decides (orig unique).
__device__ __forceinline__ unsigned long long make_pk(float nv, unsigned int o,
                                                      unsigned int slot) {
    return ((unsigned long long)__float_as_uint(nv) << 32)
         | ((unsigned long long)((o ^ 0x7FFFu) & 0x7FFFu) << 15)
         | (unsigned long long)slot;
}

// ---------- binning ----------

__global__ void bin_count_kernel(const float* __restrict__ pos, int* __restrict__ cnt) {
    int i = blockIdx.x * blockDim.x + threadIdx.x;
    if (i < N_PTS) {
        atomicAdd(&cnt[cell_of(pos[3*i], pos[3*i+1], pos[3*i+2])], 1);
    }
}

// inclusive Hillis-Steele over 2048 with 1024 threads (2 elements each)
__global__ void scan_kernel(const int* __restrict__ cnt, int* __restrict__ start,
                            int* __restrict__ fill) {
    __shared__ int s[NCELL];
    int t = threadIdx.x;
    int v0 = cnt[t], v1 = cnt[t + 1024];
    s[t] = v0; s[t + 1024] = v1;
    __syncthreads();
    for (int off = 1; off < NCELL; off <<= 1) {
        int a0 = (t >= off) ? s[t - off] : 0;
        int i1 = t + 1024;
        int a1 = (i1 >= off) ? s[i1 - off] : 0;
        __syncthreads();
        s[t] += a0; s[i1] += a1;
        __syncthreads();
    }
    start[t] = s[t] - v0;                fill[t] = s[t] - v0;
    start[t + 1024] = s[t + 1024] - v1;  fill[t + 1024] = s[t + 1024] - v1;
    if (t == 1023) start[NCELL] = s[NCELL - 1];
}

// pq[slot] = (x, y, z, orig_index_as_float_bits)
__global__ void scatter_kernel(const float* __restrict__ pos, int* __restrict__ fill,
                               float4* __restrict__ pq) {
    int i = blockIdx.x * blockDim.x + threadIdx.x;
    if (i < N_PTS) {
        float px = pos[3*i], py = pos[3*i+1], pz = pos[3*i+2];
        int c = cell_of(px, py, pz);
        int slot = atomicAdd(&fill[c], 1);
        pq[slot] = make_float4(px, py, pz, __int_as_float(i));
    }
}

// ---------- FPS ----------
// 512 threads = 8 waves (2/SIMD); wave w OWNS cells [256w,256w+256) and their
// points (wave-private s_mind / s_sub / s_wlist => DS in-order, no barrier
// around them). ONE __syncthreads per iteration.
// Pick path avoids the s_sub readback: every point of a flagged cell is
// re-touched in B, so a per-lane register running max (rmax) wave-reduced
// equals the fresh max over this wave's updated cells; stale vb of flagged
// cells is excluded. s_sub is only read POST-barrier (refresh of vb for flag
// bounds), overlapped with E's gb/pq chain.

__global__ __launch_bounds__(NTF) void fps_kernel(
        const float4* __restrict__ pq, const int* __restrict__ cstart,
        const float* __restrict__ pos, int* __restrict__ sel) {
    __shared__ float s_mind[N_PTS];                    // 128 KB (owner-private)
    __shared__ unsigned long long s_sub[NCELL];        // 16 KB (owner-private)
    __shared__ unsigned long long s_redw[NWF][8];      // 512 B (owner-private)
    __shared__ __align__(16) unsigned long long s_gb[2][NWF];  // cross-wave, dbuf
    __shared__ unsigned int s_wlist[NWF][256];         // 8 KB  (owner-private)

    const int tid  = threadIdx.x;
    const int lane = tid & 63;
    const int wid  = tid >> 6;
    const int g    = lane >> 4;     // 16-lane group 0..3
    const int gl   = lane & 15;
    const unsigned long long lmask_lt = (1ULL << lane) - 1ULL;

    for (int i = tid; i < N_PTS; i += NTF) s_mind[i] = INFINITY;
    if (tid == 0) sel[0] = 0;

    // own-cell descriptors & geometry (4 cells per lane)
    float lox[4], loy[4], loz[4];
    unsigned int ent[4];
    unsigned long long vb[4];       // per-cell best, persistent in registers
    bool fmask[4];
    #pragma unroll
    for (int k = 0; k < 4; ++k) {
        const int rest = lane + (k << 6);               // [0,256)
        const int c = (wid << 8) | rest;
        const int ix = ((rest & 7) << 1)        | (wid & 1);
        const int iy = (((rest >> 3) & 7) << 1) | ((wid >> 1) & 1);
        const int iz = ((rest >> 6) << 1)       | ((wid >> 2) & 1);
        lox[k] = (float)ix * 0.0625f;
        loy[k] = (float)iy * 0.0625f;
        loz[k] = (float)iz * 0.125f;
        const int cs = cstart[c], ce = cstart[c + 1];
        int len = ce - cs; if (len > 511) len = 511;   // statistically impossible
        ent[k] = (unsigned)cs | ((unsigned)len << 15) | ((unsigned)rest << 24);
        // +inf sentinel => every nonempty cell flagged on iteration 1
        vb[k] = (ce > cs) ? ((0x7F800000ULL << 32) | 0x3FFFFFFFULL) : 0ULL;
    }

    int nfw = 0;
    float px = pos[0], py = pos[1], pz = pos[2];

    auto flag_assign = [&]() {
        unsigned int cnt = 0;
        #pragma unroll
        for (int k = 0; k < 4; ++k) {
            const float cm = __uint_as_float((unsigned)(vb[k] >> 32));
            float dx = fmaxf(fmaxf(lox[k] - px, px - (lox[k] + 0.0625f)), 0.0f);
            float dy = fmaxf(fmaxf(loy[k] - py, py - (loy[k] + 0.0625f)), 0.0f);
            float dz = fmaxf(fmaxf(loz[k] - pz, pz - (loz[k] + 0.125f)), 0.0f);
            float lb2 = dx * dx + dy * dy + dz * dz;
            bool fl = (lb2 * 0.999f < cm);             // conservative skip bound
            fmask[k] = fl;
            unsigned long long b = __ballot(fl);
            unsigned rank = cnt + (unsigned)__popcll(b & lmask_lt);
            if (fl) s_wlist[wid][rank] = ent[k];
            cnt += (unsigned)__popcll(b);
        }
        nfw = (int)cnt;
    };
    flag_assign();
    __syncthreads();     // covers s_mind init (striped across waves)

    for (int m = 1; m < M_SEL; ++m) {
        // ---- B: own flagged cells, 4 in flight (one per 16-lane group);
        //      rmax = per-lane running max over all touched points ----
        if (lane < 8) s_redw[wid][lane] = 0ULL;
        unsigned long long rmax = 0ULL;
        for (int i = g; i < nfw; i += 4) {
            const unsigned e = s_wlist[wid][i];
            const int cs = (int)(e & 0x7FFFu);
            const int ce = cs + (int)((e >> 15) & 0x1FFu);
            const int c  = (wid << 8) | (int)(e >> 24);
            if (gl == 0) s_sub[c] = 0ULL;              // in-order before atomics
            for (int j = cs + gl; j < ce; j += 16) {
                const float4 q = pq[j];
                const float d2 = d2_exact(q.x, q.y, q.z, px, py, pz);
                const float old = s_mind[j];
                const float nv = d2 < old ? d2 : old;
                s_mind[j] = nv;
                const unsigned long long pk =
                    make_pk(nv, (unsigned)__float_as_int(q.w), (unsigned)j);
                atomicMax(&s_sub[c], pk);              // fire-and-forget
                rmax = umax64(rmax, pk);
            }
        }

        // ---- D: wave best = max(rmax, unflagged vb) — NO s_sub readback ----
        unsigned long long best = rmax;
        #pragma unroll
        for (int k = 0; k < 4; ++k)
            if (!fmask[k]) best = umax64(best, vb[k]);
        atomicMax(&s_redw[wid][lane & 7], best);
        #pragma unroll
        for (int i = 0; i < 8; ++i) best = umax64(best, s_redw[wid][i]);
        if (lane == 0) s_gb[m & 1][wid] = best;

        __syncthreads();     // the ONE barrier: publish wave-bests

        // ---- refresh vb for cells updated this iteration (reads issued
        //      first so their latency hides under E's chain) ----
        #pragma unroll
        for (int k = 0; k < 4; ++k)
            if (fmask[k]) vb[k] = s_sub[(wid << 8) | (lane + (k << 6))];

        // ---- E: global argmax over 8 wave-bests (4 x b128 + max tree) ----
        const ulonglong2* gp = (const ulonglong2*)&s_gb[m & 1][0];
        const ulonglong2 g0 = gp[0], g1 = gp[1], g2 = gp[2], g3 = gp[3];
        unsigned long long gb = umax64(
            umax64(umax64(g0.x, g0.y), umax64(g1.x, g1.y)),
            umax64(umax64(g2.x, g2.y), umax64(g3.x, g3.y)));
        const unsigned orig = (~(unsigned)(gb >> 15)) & 0x7FFFu;
        const unsigned slot = (unsigned)gb & 0x7FFFu;
        if (tid == 0) sel[m] = (int)orig;
        const float4 qp = pq[slot];                    // L1/L2-hot broadcast
        px = qp.x; py = qp.y; pz = qp.z;

        // ---- F: own flags + own list for next iteration ----
        flag_assign();
    }
}

// ---------- ball query: up-to-64 nearest in-radius (one wave / centroid) ----------

__global__ __launch_bounds__(256) void ballq_kernel(
        const float* __restrict__ pos,
        const float4* __restrict__ pq,
        const int* __restrict__ cstart, const int* __restrict__ sel,
        int* __restrict__ nbr, int* __restrict__ ncnt) {
    __shared__ float s_d2[4][CAP];
    __shared__ int   s_o[4][CAP];
    __shared__ int   s_cnt[4];

    const int wid  = threadIdx.x >> 6;
    const int lane = threadIdx.x & 63;
    const int m = blockIdx.x * 4 + wid;

    if (lane == 0) s_cnt[wid] = 0;
    __syncthreads();

    int sidx = sel[m];
    float cx = pos[3*sidx], cy = pos[3*sidx+1], cz = pos[3*sidx+2];
    int ix = iclamp((int)(cx * 16.0f), 15);
    int iy = iclamp((int)(cy * 16.0f), 15);
    int iz = iclamp((int)(cz * 8.0f), 7);
    const float r2 = (float)(0.08 * 0.08);

    // cells reachable within r=0.08: +-2 in x,y (0.0625), +-1 in z (0.125)
    for (int dz = -1; dz <= 1; ++dz) {
        int z = iz + dz; if (z < 0 || z > 7) continue;
        for (int dy = -2; dy <= 2; ++dy) {
            int y = iy + dy; if (y < 0 || y > 15) continue;
            for (int dx = -2; dx <= 2; ++dx) {
                int xx = ix + dx; if (xx < 0 || xx > 15) continue;
                int c = cell_idx(xx, y, z);
                int cs = cstart[c], ce = cstart[c + 1];
                for (int j = cs + lane; j < ce; j += 64) {
                    float4 q = pq[j];
                    float d2 = d2_exact(cx, cy, cz, q.x, q.y, q.z);
                    if (d2 <= r2) {
                        int slot = atomicAdd(&s_cnt[wid], 1);
                        if (slot < CAP) { s_d2[wid][slot] = d2; s_o[wid][slot] = __float_as_int(q.w); }
                    }
                }
            }
        }
    }
    __syncthreads();

    int cnt = s_cnt[wid];
    if (cnt > CAP) cnt = CAP;
    if (cnt <= K_NBR) {
        if (lane < cnt) nbr[m * K_NBR + lane] = s_o[wid][lane];
        if (lane == 0) ncnt[m] = cnt;
    } else {
        // exact (d2, orig-index) lexicographic rank -> keep 64 nearest (matches top_k)
        for (int i = lane; i < cnt; i += 64) {
            float d2 = s_d2[wid][i];
            int   o  = s_o[wid][i];
            int rank = 0;
            for (int j = 0; j < cnt; ++j) {
                float dj = s_d2[wid][j];
                int   oj = s_o[wid][j];
                rank += (dj < d2 || (dj == d2 && oj < o)) ? 1 : 0;
            }
            if (rank < K_NBR) nbr[m * K_NBR + rank] = o;
        }
        if (lane == 0) ncnt[m] = K_NBR;
    }
}

// ---------- PointConv MLP + masked max-pool (fp32, one block / centroid) ----------

__global__ __launch_bounds__(256) void mlp_kernel(
        const float* __restrict__ x, const float* __restrict__ pos,
        const float* __restrict__ W1, const float* __restrict__ b1,
        const float* __restrict__ W2, const float* __restrict__ b2,
        const int* __restrict__ sel, const int* __restrict__ nbr,
        const int* __restrict__ ncnt, float* __restrict__ out) {
    __shared__ __align__(16) float feat[64][68];   // 67 used + pad
    __shared__ __align__(16) float h[64][H_MID];
    __shared__ float part[2][H_MID];

    const int m = blockIdx.x;
    const int tid = threadIdx.x;
    const int cnt = ncnt[m];
    const int s = sel[m];
    float cx = pos[3*s], cy = pos[3*s+1], cz = pos[3*s+2];

    for (int i = tid; i < 64 * 68; i += 256) ((float*)feat)[i] = 0.0f;
    __syncthreads();

    for (int i = tid; i < cnt * F_IN; i += 256) {
        int k = i >> 6, f = i & 63;
        int j = nbr[m * K_NBR + k];
        feat[k][f] = x[(size_t)j * F_IN + f];
    }
    if (tid < 64 && tid < cnt) {
        int j = nbr[m * K_NBR + tid];
        feat[tid][64] = pos[3*j]     - cx;
        feat[tid][65] = pos[3*j + 1] - cy;
        feat[tid][66] = pos[3*j + 2] - cz;
    }
    __syncthreads();

    const int c = tid & 127;
    const int half = tid >> 7;

    for (int k = half; k < 64; k += 2) {
        float acc = b1[c];
        const float4* fr = (const float4*)&feat[k][0];
#pragma unroll
        for (int f4 = 0; f4 < 16; ++f4) {
            float4 fv = fr[f4];
            int fb = f4 * 4;
            acc = fmaf(fv.x, W1[(fb    ) * H_MID + c], acc);
            acc = fmaf(fv.y, W1[(fb + 1) * H_MID + c], acc);
            acc = fmaf(fv.z, W1[(fb + 2) * H_MID + c], acc);
            acc = fmaf(fv.w, W1[(fb + 3) * H_MID + c], acc);
        }
        acc = fmaf(feat[k][64], W1[64 * H_MID + c], acc);
        acc = fmaf(feat[k][65], W1[65 * H_MID + c], acc);
        acc = fmaf(feat[k][66], W1[66 * H_MID + c], acc);
        h[k][c] = fmaxf(acc, 0.0f);
    }
    __syncthreads();

    float best = -INFINITY;
    for (int k = half; k < cnt; k += 2) {
        float acc = 0.0f;
        const float4* hr = (const float4*)&h[k][0];
#pragma unroll
        for (int q = 0; q < 32; ++q) {
            float4 hv = hr[q];
            int hb = q * 4;
            acc = fmaf(hv.x, W2[(hb    ) * C_OUT + c], acc);
            acc = fmaf(hv.y, W2[(hb + 1) * C_OUT + c], acc);
            acc = fmaf(hv.z, W2[(hb + 2) * C_OUT + c], acc);
            acc = fmaf(hv.w, W2[(hb + 3) * C_OUT + c], acc);
        }
        best = fmaxf(best, acc);
    }
    part[half][c] = best;
    __syncthreads();
    if (tid < 128) {
        out[(size_t)m * C_OUT + tid] = fmaxf(part[0][tid], part[1][tid]) + b2[tid];
    }
}

// ---------- outputs 2 & 3 ----------

__global__ void tail_kernel(const float* __restrict__ pos, const int* __restrict__ sel,
                            float* __restrict__ out_selpos, float* __restrict__ out_batch) {
    int i = blockIdx.x * blockDim.x + threadIdx.x;
    if (i < M_SEL) {
        int s = sel[i];
        out_selpos[3*i]     = pos[3*s];
        out_selpos[3*i + 1] = pos[3*s + 1];
        out_selpos[3*i + 2] = pos[3*s + 2];
        out_batch[i] = 0.0f;
    }
}

// ---------- launch ----------

extern "C" void kernel_launch(void* const* d_in, const int* in_sizes, int n_in,
                              void* d_out, int out_size, void* d_ws, size_t ws_size,
                              hipStream_t stream) {
    const float* x   = (const float*)d_in[0];
    const float* pos = (const float*)d_in[1];
    // d_in[2] = batch (int64, all zeros) — unused
    const float* W1 = (const float*)d_in[3];
    const float* b1 = (const float*)d_in[4];
    const float* W2 = (const float*)d_in[5];
    const float* b2 = (const float*)d_in[6];

    float* out        = (float*)d_out;
    float* out_selpos = out + (size_t)M_SEL * C_OUT;
    float* out_batch  = out_selpos + (size_t)M_SEL * 3;

    char* ws = (char*)d_ws;
    size_t off = 0;
    auto alloc = [&](size_t bytes) -> void* {
        void* p = ws + off;
        off = (off + bytes + 255) & ~(size_t)255;
        return p;
    };
    int*    cnt    = (int*)alloc(NCELL * 4);
    int*    cstart = (int*)alloc((NCELL + 1) * 4);
    int*    cfill  = (int*)alloc(NCELL * 4);
    float4* pq     = (float4*)alloc((size_t)N_PTS * 16);
    int*    sel    = (int*)alloc(M_SEL * 4);
    int*    nbr    = (int*)alloc((size_t)M_SEL * K_NBR * 4);
    int*    ncnt   = (int*)alloc(M_SEL * 4);
    (void)ws_size; (void)in_sizes; (void)n_in; (void)out_size;

    (void)hipMemsetAsync(cnt, 0, NCELL * 4, stream);
    bin_count_kernel<<<N_PTS / 256, 256, 0, stream>>>(pos, cnt);
    scan_kernel<<<1, 1024, 0, stream>>>(cnt, cstart, cfill);
    scatter_kernel<<<N_PTS / 256, 256, 0, stream>>>(pos, cfill, pq);
    fps_kernel<<<1, NTF, 0, stream>>>(pq, cstart, pos, sel);
    ballq_kernel<<<M_SEL / 4, 256, 0, stream>>>(pos, pq, cstart, sel, nbr, ncnt);
    mlp_kernel<<<M_SEL, 256, 0, stream>>>(x, pos, W1, b1, W2, b2, sel, nbr, ncnt, out);
    tail_kernel<<<(M_SEL + 255) / 256, 256, 0, stream>>>(pos, sel, out_selpos, out_batch);
}

// Round 13
// 12575.916 us; speedup vs baseline: 1.0203x; 1.0140x over previous
//
#include <hip/hip_runtime.h>
#include <math.h>

#define N_PTS 32768
#define M_SEL 8192
#define K_NBR 64
#define F_IN  64
#define H_MID 128
#define C_OUT 128
#define NCELL 2048      // 16 x 16 x 8 grid, owner-swizzled cell index
#define CAP   192       // per-centroid candidate cap
#define NWF   8         // waves in fps block (one owner per wave)
#define NTF   (NWF * 64)

// ---------- helpers ----------

__device__ __forceinline__ int iclamp(int v, int hi) {
    return v < 0 ? 0 : (v > hi ? hi : v);
}

// owner-swizzled cell id: low bit of (ix,iy,iz) -> owner wave (8 waves),
// so any 3x3x3 spatial neighborhood spreads across all 8 waves.
__device__ __forceinline__ int cell_idx(int ix, int iy, int iz) {
    int w    = (ix & 1) | ((iy & 1) << 1) | ((iz & 1) << 2);
    int rest = ((iz >> 1) * 8 + (iy >> 1)) * 8 + (ix >> 1);      // [0,256)
    return (w << 8) | rest;
}

__device__ __forceinline__ int cell_of(float px, float py, float pz) {
    int ix = iclamp((int)(px * 16.0f), 15);
    int iy = iclamp((int)(py * 16.0f), 15);
    int iz = iclamp((int)(pz * 8.0f), 7);
    return cell_idx(ix, iy, iz);
}

// Bit-exact replica of numpy: ((dx*dx + dy*dy) + dz*dz), rn, no fma.
__device__ __forceinline__ float d2_exact(float ax, float ay, float az,
                                          float bx, float by, float bz) {
#pragma clang fp contract(off)
    float dx = ax - bx, dy = ay - by, dz = az - bz;
    return (dx * dx + dy * dy) + dz * dz;
}

__device__ __forceinline__ unsigned long long umax64(unsigned long long a,
                                                     unsigned long long b) {
    return a > b ? a : b;
}

// pack: [63:32] mind_bits, [29:15] orig^0x7FFF, [14:0] slot.
// Lex order = (mind, -orig); slot never decides (orig unique).
__device__ __forceinline__ unsigned long long make_pk(float nv, unsigned int o,
                                                      unsigned int slot) {
    return ((unsigned long long)__float_as_uint(nv) << 32)
         | ((unsigned long long)((o ^ 0x7FFFu) & 0x7FFFu) << 15)
         | (unsigned long long)slot;
}

// ---------- binning ----------

__global__ void bin_count_kernel(const float* __restrict__ pos, int* __restrict__ cnt) {
    int i = blockIdx.x * blockDim.x + threadIdx.x;
    if (i < N_PTS) {
        atomicAdd(&cnt[cell_of(pos[3*i], pos[3*i+1], pos[3*i+2])], 1);
    }
}

// inclusive Hillis-Steele over 2048 with 1024 threads (2 elements each)
__global__ void scan_kernel(const int* __restrict__ cnt, int* __restrict__ start,
                            int* __restrict__ fill) {
    __shared__ int s[NCELL];
    int t = threadIdx.x;
    int v0 = cnt[t], v1 = cnt[t + 1024];
    s[t] = v0; s[t + 1024] = v1;
    __syncthreads();
    for (int off = 1; off < NCELL; off <<= 1) {
        int a0 = (t >= off) ? s[t - off] : 0;
        int i1 = t + 1024;
        int a1 = (i1 >= off) ? s[i1 - off] : 0;
        __syncthreads();
        s[t] += a0; s[i1] += a1;
        __syncthreads();
    }
    start[t] = s[t] - v0;                fill[t] = s[t] - v0;
    start[t + 1024] = s[t + 1024] - v1;  fill[t + 1024] = s[t + 1024] - v1;
    if (t == 1023) start[NCELL] = s[NCELL - 1];
}

// pq[slot] = (x, y, z, orig_index_as_float_bits)
__global__ void scatter_kernel(const float* __restrict__ pos, int* __restrict__ fill,
                               float4* __restrict__ pq) {
    int i = blockIdx.x * blockDim.x + threadIdx.x;
    if (i < N_PTS) {
        float px = pos[3*i], py = pos[3*i+1], pz = pos[3*i+2];
        int c = cell_of(px, py, pz);
        int slot = atomicAdd(&fill[c], 1);
        pq[slot] = make_float4(px, py, pz, __int_as_float(i));
    }
}

// ---------- FPS ----------
// 512 threads = 8 waves (2/SIMD); wave w OWNS cells [256w,256w+256) and their
// points (wave-private s_mind / s_sub / s_wlist => DS in-order, no barrier
// around them). ONE __syncthreads per iteration.
// Pick path: per-lane register running max (rmax) over touched points replaces
// the s_sub readback (s_sub only read post-barrier to refresh flag bounds).
// sel[] stores are BUFFERED in wave-0 lane registers and flushed as one
// coalesced 64-wide store every 64 iterations — removes the per-iteration
// global-store ack from the barrier's vmcnt(0) drain.

__global__ __launch_bounds__(NTF) void fps_kernel(
        const float4* __restrict__ pq, const int* __restrict__ cstart,
        const float* __restrict__ pos, int* __restrict__ sel) {
    __shared__ float s_mind[N_PTS];                    // 128 KB (owner-private)
    __shared__ unsigned long long s_sub[NCELL];        // 16 KB (owner-private)
    __shared__ unsigned long long s_redw[NWF][8];      // 512 B (owner-private)
    __shared__ __align__(16) unsigned long long s_gb[2][NWF];  // cross-wave, dbuf
    __shared__ unsigned int s_wlist[NWF][256];         // 8 KB  (owner-private)

    const int tid  = threadIdx.x;
    const int lane = tid & 63;
    const int wid  = tid >> 6;
    const int g    = lane >> 4;     // 16-lane group 0..3
    const int gl   = lane & 15;
    const unsigned long long lmask_lt = (1ULL << lane) - 1ULL;

    for (int i = tid; i < N_PTS; i += NTF) s_mind[i] = INFINITY;
    if (tid == 0) sel[0] = 0;

    // own-cell descriptors & geometry (4 cells per lane)
    float lox[4], loy[4], loz[4];
    unsigned int ent[4];
    unsigned long long vb[4];       // per-cell best, persistent in registers
    bool fmask[4];
    #pragma unroll
    for (int k = 0; k < 4; ++k) {
        const int rest = lane + (k << 6);               // [0,256)
        const int c = (wid << 8) | rest;
        const int ix = ((rest & 7) << 1)        | (wid & 1);
        const int iy = (((rest >> 3) & 7) << 1) | ((wid >> 1) & 1);
        const int iz = ((rest >> 6) << 1)       | ((wid >> 2) & 1);
        lox[k] = (float)ix * 0.0625f;
        loy[k] = (float)iy * 0.0625f;
        loz[k] = (float)iz * 0.125f;
        const int cs = cstart[c], ce = cstart[c + 1];
        int len = ce - cs; if (len > 511) len = 511;   // statistically impossible
        ent[k] = (unsigned)cs | ((unsigned)len << 15) | ((unsigned)rest << 24);
        // +inf sentinel => every nonempty cell flagged on iteration 1
        vb[k] = (ce > cs) ? ((0x7F800000ULL << 32) | 0x3FFFFFFFULL) : 0ULL;
    }

    int nfw = 0;
    float px = pos[0], py = pos[1], pz = pos[2];
    unsigned int sel_reg = 0;       // wave-0 per-lane sel buffer

    auto flag_assign = [&]() {
        unsigned int cnt = 0;
        #pragma unroll
        for (int k = 0; k < 4; ++k) {
            const float cm = __uint_as_float((unsigned)(vb[k] >> 32));
            float dx = fmaxf(fmaxf(lox[k] - px, px - (lox[k] + 0.0625f)), 0.0f);
            float dy = fmaxf(fmaxf(loy[k] - py, py - (loy[k] + 0.0625f)), 0.0f);
            float dz = fmaxf(fmaxf(loz[k] - pz, pz - (loz[k] + 0.125f)), 0.0f);
            float lb2 = dx * dx + dy * dy + dz * dz;
            bool fl = (lb2 * 0.999f < cm);             // conservative skip bound
            fmask[k] = fl;
            unsigned long long b = __ballot(fl);
            unsigned rank = cnt + (unsigned)__popcll(b & lmask_lt);
            if (fl) s_wlist[wid][rank] = ent[k];
            cnt += (unsigned)__popcll(b);
        }
        nfw = (int)cnt;
    };
    flag_assign();
    __syncthreads();     // covers s_mind init (striped across waves)

    for (int m = 1; m < M_SEL; ++m) {
        // ---- B: own flagged cells, 4 in flight (one per 16-lane group);
        //      rmax = per-lane running max over all touched points ----
        if (lane < 8) s_redw[wid][lane] = 0ULL;
        unsigned long long rmax = 0ULL;
        for (int i = g; i < nfw; i += 4) {
            const unsigned e = s_wlist[wid][i];
            const int cs = (int)(e & 0x7FFFu);
            const int ce = cs + (int)((e >> 15) & 0x1FFu);
            const int c  = (wid << 8) | (int)(e >> 24);
            if (gl == 0) s_sub[c] = 0ULL;              // in-order before atomics
            for (int j = cs + gl; j < ce; j += 16) {
                const float4 q = pq[j];
                const float d2 = d2_exact(q.x, q.y, q.z, px, py, pz);
                const float old = s_mind[j];
                const float nv = d2 < old ? d2 : old;
                s_mind[j] = nv;
                const unsigned long long pk =
                    make_pk(nv, (unsigned)__float_as_int(q.w), (unsigned)j);
                atomicMax(&s_sub[c], pk);              // fire-and-forget
                rmax = umax64(rmax, pk);
            }
        }

        // ---- D: wave best = max(rmax, unflagged vb) — NO s_sub readback ----
        unsigned long long best = rmax;
        #pragma unroll
        for (int k = 0; k < 4; ++k)
            if (!fmask[k]) best = umax64(best, vb[k]);
        atomicMax(&s_redw[wid][lane & 7], best);
        #pragma unroll
        for (int i = 0; i < 8; ++i) best = umax64(best, s_redw[wid][i]);
        if (lane == 0) s_gb[m & 1][wid] = best;

        __syncthreads();     // the ONE barrier: publish wave-bests

        // ---- refresh vb for cells updated this iteration (reads issued
        //      first so their latency hides under E's chain) ----
        #pragma unroll
        for (int k = 0; k < 4; ++k)
            if (fmask[k]) vb[k] = s_sub[(wid << 8) | (lane + (k << 6))];

        // ---- E: global argmax over 8 wave-bests (4 x b128 + max tree) ----
        const ulonglong2* gp = (const ulonglong2*)&s_gb[m & 1][0];
        const ulonglong2 g0 = gp[0], g1 = gp[1], g2 = gp[2], g3 = gp[3];
        unsigned long long gb = umax64(
            umax64(umax64(g0.x, g0.y), umax64(g1.x, g1.y)),
            umax64(umax64(g2.x, g2.y), umax64(g3.x, g3.y)));
        const unsigned orig = (~(unsigned)(gb >> 15)) & 0x7FFFu;
        const unsigned slot = (unsigned)gb & 0x7FFFu;

        // buffered sel store: capture in wave-0 lane register; flush 64-wide
        if (wid == 0) {
            if (lane == ((m - 1) & 63)) sel_reg = orig;
            if ((m & 63) == 0) sel[m - 63 + lane] = (int)sel_reg;
        }

        const float4 qp = pq[slot];                    // L1/L2-hot broadcast
        px = qp.x; py = qp.y; pz = qp.z;

        // ---- F: own flags + own list for next iteration ----
        flag_assign();
    }
    // tail flush: iterations 8129..8191 live in lanes 0..62
    if (wid == 0 && lane < 63) sel[8129 + lane] = (int)sel_reg;
}

// ---------- ball query: up-to-64 nearest in-radius (one wave / centroid) ----------

__global__ __launch_bounds__(256) void ballq_kernel(
        const float* __restrict__ pos,
        const float4* __restrict__ pq,
        const int* __restrict__ cstart, const int* __restrict__ sel,
        int* __restrict__ nbr, int* __restrict__ ncnt) {
    __shared__ float s_d2[4][CAP];
    __shared__ int   s_o[4][CAP];
    __shared__ int   s_cnt[4];

    const int wid  = threadIdx.x >> 6;
    const int lane = threadIdx.x & 63;
    const int m = blockIdx.x * 4 + wid;

    if (lane == 0) s_cnt[wid] = 0;
    __syncthreads();

    int sidx = sel[m];
    float cx = pos[3*sidx], cy = pos[3*sidx+1], cz = pos[3*sidx+2];
    int ix = iclamp((int)(cx * 16.0f), 15);
    int iy = iclamp((int)(cy * 16.0f), 15);
    int iz = iclamp((int)(cz * 8.0f), 7);
    const float r2 = (float)(0.08 * 0.08);

    // cells reachable within r=0.08: +-2 in x,y (0.0625), +-1 in z (0.125)
    for (int dz = -1; dz <= 1; ++dz) {
        int z = iz + dz; if (z < 0 || z > 7) continue;
        for (int dy = -2; dy <= 2; ++dy) {
            int y = iy + dy; if (y < 0 || y > 15) continue;
            for (int dx = -2; dx <= 2; ++dx) {
                int xx = ix + dx; if (xx < 0 || xx > 15) continue;
                int c = cell_idx(xx, y, z);
                int cs = cstart[c], ce = cstart[c + 1];
                for (int j = cs + lane; j < ce; j += 64) {
                    float4 q = pq[j];
                    float d2 = d2_exact(cx, cy, cz, q.x, q.y, q.z);
                    if (d2 <= r2) {
                        int slot = atomicAdd(&s_cnt[wid], 1);
                        if (slot < CAP) { s_d2[wid][slot] = d2; s_o[wid][slot] = __float_as_int(q.w); }
                    }
                }
            }
        }
    }
    __syncthreads();

    int cnt = s_cnt[wid];
    if (cnt > CAP) cnt = CAP;
    if (cnt <= K_NBR) {
        if (lane < cnt) nbr[m * K_NBR + lane] = s_o[wid][lane];
        if (lane == 0) ncnt[m] = cnt;
    } else {
        // exact (d2, orig-index) lexicographic rank -> keep 64 nearest (matches top_k)
        for (int i = lane; i < cnt; i += 64) {
            float d2 = s_d2[wid][i];
            int   o  = s_o[wid][i];
            int rank = 0;
            for (int j = 0; j < cnt; ++j) {
                float dj = s_d2[wid][j];
                int   oj = s_o[wid][j];
                rank += (dj < d2 || (dj == d2 && oj < o)) ? 1 : 0;
            }
            if (rank < K_NBR) nbr[m * K_NBR + rank] = o;
        }
        if (lane == 0) ncnt[m] = K_NBR;
    }
}

// ---------- PointConv MLP + masked max-pool (fp32, one block / centroid) ----------

__global__ __launch_bounds__(256) void mlp_kernel(
        const float* __restrict__ x, const float* __restrict__ pos,
        const float* __restrict__ W1, const float* __restrict__ b1,
        const float* __restrict__ W2, const float* __restrict__ b2,
        const int* __restrict__ sel, const int* __restrict__ nbr,
        const int* __restrict__ ncnt, float* __restrict__ out) {
    __shared__ __align__(16) float feat[64][68];   // 67 used + pad
    __shared__ __align__(16) float h[64][H_MID];
    __shared__ float part[2][H_MID];

    const int m = blockIdx.x;
    const int tid = threadIdx.x;
    const int cnt = ncnt[m];
    const int s = sel[m];
    float cx = pos[3*s], cy = pos[3*s+1], cz = pos[3*s+2];

    for (int i = tid; i < 64 * 68; i += 256) ((float*)feat)[i] = 0.0f;
    __syncthreads();

    for (int i = tid; i < cnt * F_IN; i += 256) {
        int k = i >> 6, f = i & 63;
        int j = nbr[m * K_NBR + k];
        feat[k][f] = x[(size_t)j * F_IN + f];
    }
    if (tid < 64 && tid < cnt) {
        int j = nbr[m * K_NBR + tid];
        feat[tid][64] = pos[3*j]     - cx;
        feat[tid][65] = pos[3*j + 1] - cy;
        feat[tid][66] = pos[3*j + 2] - cz;
    }
    __syncthreads();

    const int c = tid & 127;
    const int half = tid >> 7;

    for (int k = half; k < 64; k += 2) {
        float acc = b1[c];
        const float4* fr = (const float4*)&feat[k][0];
#pragma unroll
        for (int f4 = 0; f4 < 16; ++f4) {
            float4 fv = fr[f4];
            int fb = f4 * 4;
            acc = fmaf(fv.x, W1[(fb    ) * H_MID + c], acc);
            acc = fmaf(fv.y, W1[(fb + 1) * H_MID + c], acc);
            acc = fmaf(fv.z, W1[(fb + 2) * H_MID + c], acc);
            acc = fmaf(fv.w, W1[(fb + 3) * H_MID + c], acc);
        }
        acc = fmaf(feat[k][64], W1[64 * H_MID + c], acc);
        acc = fmaf(feat[k][65], W1[65 * H_MID + c], acc);
        acc = fmaf(feat[k][66], W1[66 * H_MID + c], acc);
        h[k][c] = fmaxf(acc, 0.0f);
    }
    __syncthreads();

    float best = -INFINITY;
    for (int k = half; k < cnt; k += 2) {
        float acc = 0.0f;
        const float4* hr = (const float4*)&h[k][0];
#pragma unroll
        for (int q = 0; q < 32; ++q) {
            float4 hv = hr[q];
            int hb = q * 4;
            acc = fmaf(hv.x, W2[(hb    ) * C_OUT + c], acc);
            acc = fmaf(hv.y, W2[(hb + 1) * C_OUT + c], acc);
            acc = fmaf(hv.z, W2[(hb + 2) * C_OUT + c], acc);
            acc = fmaf(hv.w, W2[(hb + 3) * C_OUT + c], acc);
        }
        best = fmaxf(best, acc);
    }
    part[half][c] = best;
    __syncthreads();
    if (tid < 128) {
        out[(size_t)m * C_OUT + tid] = fmaxf(part[0][tid], part[1][tid]) + b2[tid];
    }
}

// ---------- outputs 2 & 3 ----------

__global__ void tail_kernel(const float* __restrict__ pos, const int* __restrict__ sel,
                            float* __restrict__ out_selpos, float* __restrict__ out_batch) {
    int i = blockIdx.x * blockDim.x + threadIdx.x;
    if (i < M_SEL) {
        int s = sel[i];
        out_selpos[3*i]     = pos[3*s];
        out_selpos[3*i + 1] = pos[3*s + 1];
        out_selpos[3*i + 2] = pos[3*s + 2];
        out_batch[i] = 0.0f;
    }
}

// ---------- launch ----------

extern "C" void kernel_launch(void* const* d_in, const int* in_sizes, int n_in,
                              void* d_out, int out_size, void* d_ws, size_t ws_size,
                              hipStream_t stream) {
    const float* x   = (const float*)d_in[0];
    const float* pos = (const float*)d_in[1];
    // d_in[2] = batch (int64, all zeros) — unused
    const float* W1 = (const float*)d_in[3];
    const float* b1 = (const float*)d_in[4];
    const float* W2 = (const float*)d_in[5];
    const float* b2 = (const float*)d_in[6];

    float* out        = (float*)d_out;
    float* out_selpos = out + (size_t)M_SEL * C_OUT;
    float* out_batch  = out_selpos + (size_t)M_SEL * 3;

    char* ws = (char*)d_ws;
    size_t off = 0;
    auto alloc = [&](size_t bytes) -> void* {
        void* p = ws + off;
        off = (off + bytes + 255) & ~(size_t)255;
        return p;
    };
    int*    cnt    = (int*)alloc(NCELL * 4);
    int*    cstart = (int*)alloc((NCELL + 1) * 4);
    int*    cfill  = (int*)alloc(NCELL * 4);
    float4* pq     = (float4*)alloc((size_t)N_PTS * 16);
    int*    sel    = (int*)alloc(M_SEL * 4);
    int*    nbr    = (int*)alloc((size_t)M_SEL * K_NBR * 4);
    int*    ncnt   = (int*)alloc(M_SEL * 4);
    (void)ws_size; (void)in_sizes; (void)n_in; (void)out_size;

    (void)hipMemsetAsync(cnt, 0, NCELL * 4, stream);
    bin_count_kernel<<<N_PTS / 256, 256, 0, stream>>>(pos, cnt);
    scan_kernel<<<1, 1024, 0, stream>>>(cnt, cstart, cfill);
    scatter_kernel<<<N_PTS / 256, 256, 0, stream>>>(pos, cfill, pq);
    fps_kernel<<<1, NTF, 0, stream>>>(pq, cstart, pos, sel);
    ballq_kernel<<<M_SEL / 4, 256, 0, stream>>>(pos, pq, cstart, sel, nbr, ncnt);
    mlp_kernel<<<M_SEL, 256, 0, stream>>>(x, pos, W1, b1, W2, b2, sel, nbr, ncnt, out);
    tail_kernel<<<(M_SEL + 255) / 256, 256, 0, stream>>>(pos, sel, out_selpos, out_batch);
}